// Round 1
// baseline (3011.901 us; speedup 1.0000x reference)
//
#include <hip/hip_runtime.h>
#include <cstdint>

// ---------------- types / helpers ----------------
using bf16 = __bf16;
typedef __bf16 bf16x8 __attribute__((ext_vector_type(8)));
typedef float  f32x4  __attribute__((ext_vector_type(4)));

__device__ inline f32x4 mfma16(bf16x8 a, bf16x8 b, f32x4 c) {
  // D[r][c]: lane holds rows (l>>4)*4+i, col l&15. A: lane row=l&15, k=(l>>4)*8+j.
  // B: lane col=l&15, k=(l>>4)*8+j.
  return __builtin_amdgcn_mfma_f32_16x16x32_bf16(a, b, c, 0, 0, 0);
}
__device__ inline float b2f(unsigned short h) {
  unsigned u = ((unsigned)h) << 16;
  return __builtin_bit_cast(float, u);
}

#define BATCH 32
#define LTOK  2048
#define HWTOK 1024
#define CDIM  512

// ---------------- generic tiled GEMM: out = A @ W + bias (bf16 out) --------
// Tile 64x64, BK=64, 256 threads (4 waves 2x2). N fixed = 512.
// AMODE 0: A f32 row-major [M][K], lda
// AMODE 1: A f32 "col-major" (element (m,k) at A[k*lda + m])  (torch .view transpose)
// AMODE 2: A bf16 concat: k<512 -> A1[m*512+k], else A2[m*512+k-512]
// BMODE 0: W f32 [K][512] row-major
// BMODE 1: W f32 [512][K] row-major (Wf)
template<int AMODE, int BMODE>
__global__ __launch_bounds__(256) void gemm_k(
    const void* __restrict__ Aptr, const void* __restrict__ A2ptr,
    const float* __restrict__ W, const float* __restrict__ bias,
    bf16* __restrict__ out, int K, int lda, long batchA, long batchOut)
{
  const int N = 512;
  int b  = blockIdx.z;
  int m0 = blockIdx.y * 64, n0 = blockIdx.x * 64;
  int tid = threadIdx.x, lane = tid & 63, wid = tid >> 6;
  int lr = lane & 15, lg = lane >> 4;
  __shared__ __align__(16) bf16 lA[64][72];
  __shared__ __align__(16) bf16 lB[64][72];
  f32x4 acc[2][2] = {};
  const int mw = (wid >> 1) * 32, nw = (wid & 1) * 32;

  for (int k0 = 0; k0 < K; k0 += 64) {
    // ---- stage A tile [64 m][64 k] as bf16 ----
    if constexpr (AMODE == 0) {
      const float* A = (const float*)Aptr + (long)b * batchA;
      #pragma unroll
      for (int j = 0; j < 4; j++) {
        int f = tid + j * 256; int r = f >> 4, cq = f & 15;
        float4 v = *(const float4*)(A + (long)(m0 + r) * lda + k0 + cq * 4);
        bf16* d = &lA[r][cq * 4];
        d[0] = (bf16)v.x; d[1] = (bf16)v.y; d[2] = (bf16)v.z; d[3] = (bf16)v.w;
      }
    } else if constexpr (AMODE == 1) {
      const float* A = (const float*)Aptr + (long)b * batchA;
      #pragma unroll
      for (int j = 0; j < 4; j++) {
        int f = tid + j * 256; int kl = f >> 4, mq = f & 15;
        float4 v = *(const float4*)(A + (long)(k0 + kl) * lda + m0 + mq * 4);
        lA[mq * 4 + 0][kl] = (bf16)v.x; lA[mq * 4 + 1][kl] = (bf16)v.y;
        lA[mq * 4 + 2][kl] = (bf16)v.z; lA[mq * 4 + 3][kl] = (bf16)v.w;
      }
    } else {
      #pragma unroll
      for (int j = 0; j < 2; j++) {
        int f = tid + j * 256; int r = f >> 3, c8 = f & 7;
        int kg = k0 + c8 * 8;
        const bf16* src = (kg < 512)
            ? ((const bf16*)Aptr  + (long)(m0 + r) * 512 + kg)
            : ((const bf16*)A2ptr + (long)(m0 + r) * 512 + kg - 512);
        *(uint4*)&lA[r][c8 * 8] = *(const uint4*)src;
      }
    }
    // ---- stage B tile as Bt[n][k] ----
    if constexpr (BMODE == 0) {
      #pragma unroll
      for (int j = 0; j < 4; j++) {
        int f = tid + j * 256; int kl = f >> 4, nq = f & 15;
        float4 v = *(const float4*)(W + (long)(k0 + kl) * N + n0 + nq * 4);
        lB[nq * 4 + 0][kl] = (bf16)v.x; lB[nq * 4 + 1][kl] = (bf16)v.y;
        lB[nq * 4 + 2][kl] = (bf16)v.z; lB[nq * 4 + 3][kl] = (bf16)v.w;
      }
    } else {
      #pragma unroll
      for (int j = 0; j < 4; j++) {
        int f = tid + j * 256; int r = f >> 4, kq = f & 15;
        float4 v = *(const float4*)(W + (long)(n0 + r) * K + k0 + kq * 4);
        bf16* d = &lB[r][kq * 4];
        d[0] = (bf16)v.x; d[1] = (bf16)v.y; d[2] = (bf16)v.z; d[3] = (bf16)v.w;
      }
    }
    __syncthreads();
    #pragma unroll
    for (int ss = 0; ss < 2; ss++) {
      int ko = ss * 32 + lg * 8;
      bf16x8 a0 = *(const bf16x8*)&lA[mw + lr][ko];
      bf16x8 a1 = *(const bf16x8*)&lA[mw + 16 + lr][ko];
      bf16x8 b0 = *(const bf16x8*)&lB[nw + lr][ko];
      bf16x8 b1 = *(const bf16x8*)&lB[nw + 16 + lr][ko];
      acc[0][0] = mfma16(a0, b0, acc[0][0]);
      acc[0][1] = mfma16(a0, b1, acc[0][1]);
      acc[1][0] = mfma16(a1, b0, acc[1][0]);
      acc[1][1] = mfma16(a1, b1, acc[1][1]);
    }
    __syncthreads();
  }
  bf16* o = out + (long)b * batchOut;
  #pragma unroll
  for (int fm = 0; fm < 2; fm++) {
    #pragma unroll
    for (int fn = 0; fn < 2; fn++) {
      int col = n0 + nw + fn * 16 + lr;
      float bc = bias[col];
      #pragma unroll
      for (int i = 0; i < 4; i++) {
        int row = m0 + mw + fm * 16 + lg * 4 + i;
        o[(long)row * N + col] = (bf16)(acc[fm][fn][i] + bc);
      }
    }
  }
}

// ---------------- transpose [B][1024][512] -> [B][512][1024] (bf16) -------
__global__ __launch_bounds__(256) void transpose_k(const bf16* __restrict__ in,
                                                   bf16* __restrict__ out)
{
  int b = blockIdx.z, p0 = blockIdx.x * 64, m0 = blockIdx.y * 64;
  __shared__ __align__(16) bf16 t[64][72];
  const bf16* I = in  + (long)b * (HWTOK * CDIM);
  bf16*       O = out + (long)b * (HWTOK * CDIM);
  int tid = threadIdx.x;
  #pragma unroll
  for (int j = 0; j < 2; j++) {
    int f = tid + j * 256; int r = f >> 3, c8 = f & 7;
    *(uint4*)&t[r][c8 * 8] = *(const uint4*)(I + (long)(m0 + r) * 512 + p0 + c8 * 8);
  }
  __syncthreads();
  #pragma unroll
  for (int j = 0; j < 2; j++) {
    int f = tid + j * 256; int pr = f >> 3, m8 = f & 7;
    bf16 tmp[8];
    #pragma unroll
    for (int e = 0; e < 8; e++) tmp[e] = t[m8 * 8 + e][pr];
    *(uint4*)(O + (long)(p0 + pr) * 1024 + m0 + m8 * 8) = *(uint4*)tmp;
  }
}

// ---------------- fused attention + residual + LayerNorm -------------------
// block: (batch, 16 q-rows), 512 threads (8 waves). Full 1024-wide score rows
// in LDS (f32), softmax in place (P bf16 reuses the same row stripe), PV from
// pre-transposed Vt, epilogue LN -> T bf16.
__global__ __launch_bounds__(512) void attn_k(
    const bf16* __restrict__ Qb, const bf16* __restrict__ Kb,
    const bf16* __restrict__ Vt, const float* __restrict__ Fj,
    const float* __restrict__ ln_g, const float* __restrict__ ln_b,
    bf16* __restrict__ T)
{
  constexpr int SROW = 4128;                // bytes per row stripe (1032 f32)
  __shared__ __align__(16) unsigned char SP[16 * SROW];
  __shared__ float lsum[16];
  __shared__ float ex[8][16][2];
  int b = blockIdx.y, q0 = blockIdx.x * 16;
  int tid = threadIdx.x, lane = tid & 63, wid = tid >> 6;
  int lr = lane & 15, lg = lane >> 4;

  // Q fragments (rows q0..q0+15, full K=512): 16 frags cached in regs
  bf16x8 aq[16];
  const bf16* qptr = Qb + ((long)(b * LTOK + q0 + lr) * 512 + lg * 8);
  #pragma unroll
  for (int ks = 0; ks < 16; ks++) aq[ks] = *(const bf16x8*)(qptr + ks * 32);

  // ---- S = Q K^T * scale ----
  const float scale = 0.044194173824159216f;   // 512^-0.5
  const bf16* kbase = Kb + (long)b * (HWTOK * CDIM);
  #pragma unroll 1
  for (int nf = 0; nf < 8; nf++) {
    int col = wid * 128 + nf * 16;
    f32x4 acc = {0.f, 0.f, 0.f, 0.f};
    const bf16* kp = kbase + (long)(col + lr) * 512 + lg * 8;
    #pragma unroll
    for (int ks = 0; ks < 16; ks++)
      acc = mfma16(aq[ks], *(const bf16x8*)(kp + ks * 32), acc);
    #pragma unroll
    for (int i = 0; i < 4; i++) {
      float* Srow = (float*)(SP + (lg * 4 + i) * SROW);
      Srow[col + lr] = acc[i] * scale;
    }
  }
  __syncthreads();

  // ---- softmax: row = tid>>5, 32 lanes per row (half-wave, lockstep) ----
  {
    int row = tid >> 5, c0 = tid & 31;
    float* Srow = (float*)(SP + row * SROW);
    float sv[32]; float m = -1e30f;
    #pragma unroll
    for (int j = 0; j < 32; j++) { sv[j] = Srow[c0 + j * 32]; m = fmaxf(m, sv[j]); }
    #pragma unroll
    for (int k = 1; k < 32; k <<= 1) m = fmaxf(m, __shfl_xor(m, k));
    float s = 0.f;
    #pragma unroll
    for (int j = 0; j < 32; j++) { sv[j] = __expf(sv[j] - m); s += sv[j]; }
    #pragma unroll
    for (int k = 1; k < 32; k <<= 1) s += __shfl_xor(s, k);
    if (c0 == 0) lsum[row] = s;
    unsigned short* Prow = (unsigned short*)(SP + row * SROW);
    #pragma unroll
    for (int j = 0; j < 32; j++)
      Prow[c0 + j * 32] = __builtin_bit_cast(unsigned short, (bf16)sv[j]);
  }
  __syncthreads();

  // ---- I = P @ V  (B-frags from Vt[b][p][m], 16B contiguous) ----
  f32x4 pacc[4] = {};
  const bf16* vbase = Vt + (long)b * (HWTOK * CDIM) + (long)(wid * 64 + lr) * 1024 + lg * 8;
  #pragma unroll 2
  for (int ks = 0; ks < 32; ks++) {
    bf16x8 a = *(const bf16x8*)(SP + lr * SROW + (ks * 32 + lg * 8) * 2);
    const bf16* vp = vbase + ks * 32;
    pacc[0] = mfma16(a, *(const bf16x8*)(vp),             pacc[0]);
    pacc[1] = mfma16(a, *(const bf16x8*)(vp + 16 * 1024), pacc[1]);
    pacc[2] = mfma16(a, *(const bf16x8*)(vp + 32 * 1024), pacc[2]);
    pacc[3] = mfma16(a, *(const bf16x8*)(vp + 48 * 1024), pacc[3]);
  }

  // ---- epilogue: /rowsum + residual + LayerNorm -> T bf16 ----
  float v[4][4];
  #pragma unroll
  for (int i = 0; i < 4; i++) {
    int row = lg * 4 + i;
    float inv = 1.0f / lsum[row];
    long base = (long)(b * LTOK + q0 + row) * 512 + wid * 64;
    #pragma unroll
    for (int fn = 0; fn < 4; fn++)
      v[i][fn] = pacc[fn][i] * inv + Fj[base + fn * 16 + lr];
  }
  float ps[4], ps2[4];
  #pragma unroll
  for (int i = 0; i < 4; i++) {
    float a = 0.f, a2 = 0.f;
    #pragma unroll
    for (int fn = 0; fn < 4; fn++) { float x = v[i][fn]; a += x; a2 += x * x; }
    #pragma unroll
    for (int k = 1; k < 16; k <<= 1) { a += __shfl_xor(a, k); a2 += __shfl_xor(a2, k); }
    ps[i] = a; ps2[i] = a2;
  }
  if (lr == 0) {
    #pragma unroll
    for (int i = 0; i < 4; i++) { ex[wid][lg * 4 + i][0] = ps[i]; ex[wid][lg * 4 + i][1] = ps2[i]; }
  }
  __syncthreads();
  #pragma unroll
  for (int i = 0; i < 4; i++) {
    int row = lg * 4 + i;
    float S = 0.f, S2 = 0.f;
    #pragma unroll
    for (int w = 0; w < 8; w++) { S += ex[w][row][0]; S2 += ex[w][row][1]; }
    float mu = S * (1.0f / 512);
    float var = S2 * (1.0f / 512) - mu * mu;
    float rs = rsqrtf(var + 1e-5f);
    long rb = (long)(b * LTOK + q0 + row) * 512;
    #pragma unroll
    for (int fn = 0; fn < 4; fn++) {
      int col = wid * 64 + fn * 16 + lr;
      float t = (v[i][fn] - mu) * rs * ln_g[col] + ln_b[col];
      T[rb + col] = (bf16)t;
    }
  }
}

// ---------------- BatchNorm stats / finalize / apply ----------------------
__global__ __launch_bounds__(256) void bn_stats_k(const bf16* __restrict__ Y,
                                                  float* __restrict__ sums)
{
  int r0 = blockIdx.x * 32; int t = threadIdx.x;
  float s0 = 0, s1 = 0, q0 = 0, q1 = 0;
  for (int j = 0; j < 32; j++) {
    unsigned u = *(const unsigned*)(Y + (long)(r0 + j) * 512 + t * 2);
    float a = b2f((unsigned short)(u & 0xffff));
    float c = b2f((unsigned short)(u >> 16));
    s0 += a; q0 += a * a; s1 += c; q1 += c * c;
  }
  atomicAdd(&sums[t * 2],       s0);
  atomicAdd(&sums[t * 2 + 1],   s1);
  atomicAdd(&sums[512 + t * 2],     q0);
  atomicAdd(&sums[512 + t * 2 + 1], q1);
}

__global__ void bn_finalize_k(const float* __restrict__ sums,
                              const float* __restrict__ bn_g,
                              const float* __restrict__ bn_b,
                              float* __restrict__ ss)
{
  int c = threadIdx.x;   // 512
  const float invN = 1.0f / 65536.0f;
  float mean = sums[c] * invN;
  float var  = sums[512 + c] * invN - mean * mean;
  float sc = bn_g[c] * rsqrtf(var + 1e-5f);
  ss[c] = sc;
  ss[512 + c] = bn_b[c] - mean * sc;
}

__global__ __launch_bounds__(256) void bn_apply_k(const bf16* __restrict__ Y,
                                                  const float* __restrict__ ss,
                                                  float* __restrict__ out)
{
  long idx = ((long)blockIdx.x * 256 + threadIdx.x) * 8;
  int c0 = (int)(idx & 511);
  uint4 u = *(const uint4*)(Y + idx);
  const unsigned* up = (const unsigned*)&u;
  float4 sa = *(const float4*)(ss + c0);
  float4 sb = *(const float4*)(ss + c0 + 4);
  float4 ha = *(const float4*)(ss + 512 + c0);
  float4 hb = *(const float4*)(ss + 512 + c0 + 4);
  float f[8];
  #pragma unroll
  for (int e = 0; e < 4; e++) {
    f[2 * e]     = b2f((unsigned short)(up[e] & 0xffff));
    f[2 * e + 1] = b2f((unsigned short)(up[e] >> 16));
  }
  float4 o0, o1;
  o0.x = fmaxf(0.f, f[0] * sa.x + ha.x);
  o0.y = fmaxf(0.f, f[1] * sa.y + ha.y);
  o0.z = fmaxf(0.f, f[2] * sa.z + ha.z);
  o0.w = fmaxf(0.f, f[3] * sa.w + ha.w);
  o1.x = fmaxf(0.f, f[4] * sb.x + hb.x);
  o1.y = fmaxf(0.f, f[5] * sb.y + hb.y);
  o1.z = fmaxf(0.f, f[6] * sb.z + hb.z);
  o1.w = fmaxf(0.f, f[7] * sb.w + hb.w);
  *(float4*)(out + idx) = o0;
  *(float4*)(out + idx + 4) = o1;
}

// ---------------- launch ---------------------------------------------------
extern "C" void kernel_launch(void* const* d_in, const int* in_sizes, int n_in,
                              void* d_out, int out_size, void* d_ws, size_t ws_size,
                              hipStream_t stream)
{
  (void)in_sizes; (void)n_in; (void)out_size; (void)ws_size;
  const float* Fj  = (const float*)d_in[0];
  const float* Fs  = (const float*)d_in[1];
  const float* Fe  = (const float*)d_in[2];
  const float* Wq  = (const float*)d_in[3];
  const float* bq  = (const float*)d_in[4];
  const float* Wsk = (const float*)d_in[5];
  const float* bsk = (const float*)d_in[6];
  const float* Wsv = (const float*)d_in[7];
  const float* bsv = (const float*)d_in[8];
  const float* Wek = (const float*)d_in[9];
  const float* bek = (const float*)d_in[10];
  const float* Wev = (const float*)d_in[11];
  const float* bev = (const float*)d_in[12];
  const float* lng = (const float*)d_in[13];
  const float* lnb = (const float*)d_in[14];
  const float* Wf  = (const float*)d_in[15];
  const float* bfp = (const float*)d_in[16];
  const float* bng = (const float*)d_in[17];
  const float* bnb = (const float*)d_in[18];

  char* ws = (char*)d_ws;
  bf16* Qb = (bf16*)(ws);                       // 64 MiB (reused as Y after attn)
  bf16* Kb = (bf16*)(ws + 67108864L);           // 32 MiB
  bf16* Vb = (bf16*)(ws + 100663296L);          // 32 MiB
  bf16* Vt = (bf16*)(ws + 134217728L);          // 32 MiB
  bf16* T1 = (bf16*)(ws + 167772160L);          // 64 MiB
  bf16* T2 = (bf16*)(ws + 234881024L);          // 64 MiB
  float* stats = (float*)(ws + 301989888L);     // 1024 f32 sums
  float* ssbuf = stats + 1024;                  // 1024 f32 scale/shift
  float* outp = (float*)d_out;

  dim3 blk(256);
  const long SB = (long)HWTOK * CDIM;   // per-batch elements of F_s view / K / V

  // Q = F_j @ Wq + bq
  gemm_k<0,0><<<dim3(8,1024,1), blk, 0, stream>>>(Fj, nullptr, Wq, bq, Qb, 512, 512, 0, 0);

  // ---- attention 1 (sub-features) ----
  gemm_k<1,0><<<dim3(8,16,32), blk, 0, stream>>>(Fs, nullptr, Wsk, bsk, Kb, 512, 1024, SB, SB);
  gemm_k<1,0><<<dim3(8,16,32), blk, 0, stream>>>(Fs, nullptr, Wsv, bsv, Vb, 512, 1024, SB, SB);
  transpose_k<<<dim3(8,16,32), blk, 0, stream>>>(Vb, Vt);
  attn_k<<<dim3(128,32), dim3(512), 0, stream>>>(Qb, Kb, Vt, Fj, lng, lnb, T1);

  // ---- attention 2 (scene-features) ----
  gemm_k<1,0><<<dim3(8,16,32), blk, 0, stream>>>(Fe, nullptr, Wek, bek, Kb, 512, 1024, SB, SB);
  gemm_k<1,0><<<dim3(8,16,32), blk, 0, stream>>>(Fe, nullptr, Wev, bev, Vb, 512, 1024, SB, SB);
  transpose_k<<<dim3(8,16,32), blk, 0, stream>>>(Vb, Vt);
  attn_k<<<dim3(128,32), dim3(512), 0, stream>>>(Qb, Kb, Vt, Fj, lng, lnb, T2);

  // ---- fusion conv1d (K=1024 concat) + BN + ReLU ----
  (void)hipMemsetAsync(stats, 0, 4096, stream);
  gemm_k<2,1><<<dim3(8,1024,1), blk, 0, stream>>>(T1, T2, Wf, bfp, Qb /*Y*/, 1024, 512, 0, 0);
  bn_stats_k<<<dim3(2048), blk, 0, stream>>>(Qb, stats);
  bn_finalize_k<<<dim3(1), dim3(512), 0, stream>>>(stats, bng, bnb, ssbuf);
  bn_apply_k<<<dim3(16384), blk, 0, stream>>>(Qb, ssbuf, outp);
}

// Round 2
// 1391.240 us; speedup vs baseline: 2.1649x; 2.1649x over previous
//
#include <hip/hip_runtime.h>
#include <cstdint>

// ---------------- types / helpers ----------------
using bf16 = __bf16;
typedef __bf16 bf16x8 __attribute__((ext_vector_type(8)));
typedef float  f32x4  __attribute__((ext_vector_type(4)));

__device__ inline f32x4 mfma16(bf16x8 a, bf16x8 b, f32x4 c) {
  // A: lane row=l&15, k=(l>>4)*8+j. B: lane col=l&15, k=(l>>4)*8+j.
  // C/D: col=l&15, row=(l>>4)*4+i.
  return __builtin_amdgcn_mfma_f32_16x16x32_bf16(a, b, c, 0, 0, 0);
}
__device__ inline float b2f(unsigned short h) {
  unsigned u = ((unsigned)h) << 16;
  return __builtin_bit_cast(float, u);
}
__device__ inline unsigned pack2(float x, float y) {
  return (unsigned)__builtin_bit_cast(unsigned short, (bf16)x)
       | ((unsigned)__builtin_bit_cast(unsigned short, (bf16)y) << 16);
}
__device__ inline void gload16(const void* g, void* l) {
  __builtin_amdgcn_global_load_lds(
      (const __attribute__((address_space(1))) void*)g,
      (__attribute__((address_space(3))) void*)l, 16, 0, 0);
}

#define BATCH 32
#define LTOK  2048
#define HWTOK 1024
#define CDIM  512

// ---------------- universal bf16 GEMM, m97 structure ----------------------
// out[M][N] = A[M][K] @ B[N][K]^T (+bias col/row) (+resid f32) -> bf16
// 128x128 tile, BK=64, 256 thr (4 waves 2x2, 64x64 each), global_load_lds x16.
// BIAS: 0 none, 1 by col, 2 by row. CONCAT: A is [T1|T2] along K (512+512).
template<int BIAS, bool CONCAT, bool RESID>
__global__ __launch_bounds__(256) void gemm_bt(
    const bf16* __restrict__ A, const bf16* __restrict__ A2,
    const bf16* __restrict__ Bm, const float* __restrict__ bias,
    const float* __restrict__ resid, bf16* __restrict__ out,
    int N, int K, long bA, long bB, long bO)
{
  int bz = blockIdx.z;
  int m0 = blockIdx.y * 128, n0 = blockIdx.x * 128;
  int tid = threadIdx.x, lane = tid & 63;
  int wid = tid >> 6, lr = lane & 15, lg = lane >> 4;
  int wm = (wid >> 1) * 64, wn = (wid & 1) * 64;
  __shared__ __align__(16) bf16 lA[128 * 64];
  __shared__ __align__(16) bf16 lB[128 * 64];
  const bf16* Ab = A + (long)bz * bA;
  const bf16* Bb = Bm + (long)bz * bB;
  f32x4 acc[4][4] = {};

  for (int k0 = 0; k0 < K; k0 += 64) {
    #pragma unroll
    for (int c = 0; c < 4; c++) {
      int f = c * 256 + tid;
      int row = f >> 3, k8 = f & 7;
      const bf16* g;
      if constexpr (CONCAT) {
        int kg = k0 + k8 * 8;
        g = (kg < 512) ? (A  + ((long)(m0 + row) << 9) + kg)
                       : (A2 + ((long)(m0 + row) << 9) + (kg - 512));
      } else {
        g = Ab + (long)(m0 + row) * K + k0 + k8 * 8;
      }
      gload16(g, (char*)lA + f * 16);
    }
    #pragma unroll
    for (int c = 0; c < 4; c++) {
      int f = c * 256 + tid;
      int row = f >> 3, k8 = f & 7;
      gload16(Bb + (long)(n0 + row) * K + k0 + k8 * 8, (char*)lB + f * 16);
    }
    __syncthreads();
    #pragma unroll
    for (int ss = 0; ss < 2; ss++) {
      bf16x8 af[4], bfr[4];
      #pragma unroll
      for (int t = 0; t < 4; t++)
        af[t] = *(const bf16x8*)&lA[(wm + t * 16 + lr) * 64 + ss * 32 + lg * 8];
      #pragma unroll
      for (int t = 0; t < 4; t++)
        bfr[t] = *(const bf16x8*)&lB[(wn + t * 16 + lr) * 64 + ss * 32 + lg * 8];
      #pragma unroll
      for (int fm = 0; fm < 4; fm++)
        #pragma unroll
        for (int fn = 0; fn < 4; fn++)
          acc[fm][fn] = mfma16(af[fm], bfr[fn], acc[fm][fn]);
    }
    __syncthreads();
  }

  long obase = (long)bz * bO;
  #pragma unroll
  for (int fm = 0; fm < 4; fm++) {
    #pragma unroll
    for (int i = 0; i < 4; i++) {
      int row = m0 + wm + fm * 16 + lg * 4 + i;
      long rb = obase + (long)row * N;
      #pragma unroll
      for (int fn = 0; fn < 4; fn++) {
        int col = n0 + wn + fn * 16 + lr;
        float v = acc[fm][fn][i];
        if constexpr (BIAS == 1) v += bias[col];
        if constexpr (BIAS == 2) v += bias[row];
        if constexpr (RESID)     v += resid[rb + col];
        out[rb + col] = (bf16)v;
      }
    }
  }
}

// ---------------- elementwise f32 -> bf16 ---------------------------------
__global__ __launch_bounds__(256) void cvt_k(const float* __restrict__ in,
                                             bf16* __restrict__ out)
{
  long i = ((long)blockIdx.x * 256 + threadIdx.x) * 8;
  float4 a = *(const float4*)(in + i);
  float4 c = *(const float4*)(in + i + 4);
  unsigned o[4];
  o[0] = pack2(a.x, a.y); o[1] = pack2(a.z, a.w);
  o[2] = pack2(c.x, c.y); o[3] = pack2(c.z, c.w);
  *(uint4*)(out + i) = *(uint4*)o;
}

// ---------------- transpose + convert: in[rows][cols] f32 -> out[cols][rows] bf16
__global__ __launch_bounds__(256) void cvtT_k(const float* __restrict__ in,
                                              bf16* __restrict__ out,
                                              int rows, int cols, long bElems)
{
  int bz = blockIdx.z;
  int c0 = blockIdx.x * 64, r0 = blockIdx.y * 64;
  const float* I = in + (long)bz * bElems;
  bf16* O = out + (long)bz * bElems;
  __shared__ __align__(16) bf16 t[64][72];
  int tid = threadIdx.x;
  #pragma unroll
  for (int j = 0; j < 4; j++) {
    int kk = j * 16 + (tid >> 4);
    int mm = (tid & 15) * 4;
    float4 v = *(const float4*)(I + (long)(r0 + kk) * cols + c0 + mm);
    t[mm + 0][kk] = (bf16)v.x; t[mm + 1][kk] = (bf16)v.y;
    t[mm + 2][kk] = (bf16)v.z; t[mm + 3][kk] = (bf16)v.w;
  }
  __syncthreads();
  #pragma unroll
  for (int p = 0; p < 2; p++) {
    int r = (tid >> 3) + p * 32;
    int c8 = tid & 7;
    *(uint4*)(O + (long)(c0 + r) * rows + r0 + c8 * 8) = *(const uint4*)&t[r][c8 * 8];
  }
}

// ---------------- row softmax over 1024 bf16, in place (scale fused) ------
__global__ __launch_bounds__(256) void softmax_k(bf16* __restrict__ S)
{
  int r = blockIdx.x * 4 + (threadIdx.x >> 6);
  int lane = threadIdx.x & 63;
  bf16* row = S + (long)r * 1024 + lane * 16;
  uint4 u0 = *(const uint4*)row;
  uint4 u1 = *(const uint4*)(row + 8);
  const float scale = 0.044194173824159216f;  // 512^-0.5
  float v[16];
  {
    unsigned* up = (unsigned*)&u0;
    #pragma unroll
    for (int e = 0; e < 4; e++) { v[2*e] = b2f(up[e] & 0xffff); v[2*e+1] = b2f(up[e] >> 16); }
    up = (unsigned*)&u1;
    #pragma unroll
    for (int e = 0; e < 4; e++) { v[8+2*e] = b2f(up[e] & 0xffff); v[8+2*e+1] = b2f(up[e] >> 16); }
  }
  float m = -1e30f;
  #pragma unroll
  for (int j = 0; j < 16; j++) { v[j] *= scale; m = fmaxf(m, v[j]); }
  #pragma unroll
  for (int k = 1; k < 64; k <<= 1) m = fmaxf(m, __shfl_xor(m, k));
  float s = 0.f;
  #pragma unroll
  for (int j = 0; j < 16; j++) { v[j] = __expf(v[j] - m); s += v[j]; }
  #pragma unroll
  for (int k = 1; k < 64; k <<= 1) s += __shfl_xor(s, k);
  float inv = 1.0f / s;
  unsigned o[8];
  #pragma unroll
  for (int e = 0; e < 8; e++) o[e] = pack2(v[2*e] * inv, v[2*e+1] * inv);
  *(uint4*)row       = *(uint4*)&o[0];
  *(uint4*)(row + 8) = *(uint4*)&o[4];
}

// ---------------- row LayerNorm over 512 bf16, in place -------------------
__global__ __launch_bounds__(256) void ln_k(bf16* __restrict__ T,
                                            const float* __restrict__ g,
                                            const float* __restrict__ b)
{
  int r = blockIdx.x * 4 + (threadIdx.x >> 6);
  int lane = threadIdx.x & 63;
  bf16* row = T + (long)r * 512 + lane * 8;
  uint4 u = *(const uint4*)row;
  float v[8];
  {
    unsigned* up = (unsigned*)&u;
    #pragma unroll
    for (int e = 0; e < 4; e++) { v[2*e] = b2f(up[e] & 0xffff); v[2*e+1] = b2f(up[e] >> 16); }
  }
  float s = 0.f, s2 = 0.f;
  #pragma unroll
  for (int j = 0; j < 8; j++) { s += v[j]; s2 += v[j] * v[j]; }
  #pragma unroll
  for (int k = 1; k < 64; k <<= 1) { s += __shfl_xor(s, k); s2 += __shfl_xor(s2, k); }
  float mu = s * (1.0f / 512.0f);
  float var = s2 * (1.0f / 512.0f) - mu * mu;
  float rs = rsqrtf(var + 1e-5f);
  float4 g0 = *(const float4*)(g + lane * 8);
  float4 g1 = *(const float4*)(g + lane * 8 + 4);
  float4 b0 = *(const float4*)(b + lane * 8);
  float4 b1 = *(const float4*)(b + lane * 8 + 4);
  float gg[8] = {g0.x,g0.y,g0.z,g0.w,g1.x,g1.y,g1.z,g1.w};
  float bb[8] = {b0.x,b0.y,b0.z,b0.w,b1.x,b1.y,b1.z,b1.w};
  unsigned o[4];
  #pragma unroll
  for (int e = 0; e < 4; e++)
    o[e] = pack2((v[2*e]   - mu) * rs * gg[2*e]   + bb[2*e],
                 (v[2*e+1] - mu) * rs * gg[2*e+1] + bb[2*e+1]);
  *(uint4*)row = *(uint4*)o;
}

// ---------------- BatchNorm stats / finalize / apply ----------------------
__global__ __launch_bounds__(256) void bn_stats_k(const bf16* __restrict__ Y,
                                                  float* __restrict__ sums)
{
  int r0 = blockIdx.x * 32; int t = threadIdx.x;
  float s0 = 0, s1 = 0, q0 = 0, q1 = 0;
  for (int j = 0; j < 32; j++) {
    unsigned u = *(const unsigned*)(Y + (long)(r0 + j) * 512 + t * 2);
    float a = b2f((unsigned short)(u & 0xffff));
    float c = b2f((unsigned short)(u >> 16));
    s0 += a; q0 += a * a; s1 += c; q1 += c * c;
  }
  atomicAdd(&sums[t * 2],           s0);
  atomicAdd(&sums[t * 2 + 1],       s1);
  atomicAdd(&sums[512 + t * 2],     q0);
  atomicAdd(&sums[512 + t * 2 + 1], q1);
}

__global__ void bn_finalize_k(const float* __restrict__ sums,
                              const float* __restrict__ bn_g,
                              const float* __restrict__ bn_b,
                              float* __restrict__ ss)
{
  int c = threadIdx.x;   // 512
  const float invN = 1.0f / 65536.0f;
  float mean = sums[c] * invN;
  float var  = sums[512 + c] * invN - mean * mean;
  float sc = bn_g[c] * rsqrtf(var + 1e-5f);
  ss[c] = sc;
  ss[512 + c] = bn_b[c] - mean * sc;
}

__global__ __launch_bounds__(256) void bn_apply_k(const bf16* __restrict__ Y,
                                                  const float* __restrict__ ss,
                                                  float* __restrict__ out)
{
  long idx = ((long)blockIdx.x * 256 + threadIdx.x) * 8;
  int c0 = (int)(idx & 511);
  uint4 u = *(const uint4*)(Y + idx);
  const unsigned* up = (const unsigned*)&u;
  float4 sa = *(const float4*)(ss + c0);
  float4 sb = *(const float4*)(ss + c0 + 4);
  float4 ha = *(const float4*)(ss + 512 + c0);
  float4 hb = *(const float4*)(ss + 512 + c0 + 4);
  float f[8];
  #pragma unroll
  for (int e = 0; e < 4; e++) {
    f[2 * e]     = b2f((unsigned short)(up[e] & 0xffff));
    f[2 * e + 1] = b2f((unsigned short)(up[e] >> 16));
  }
  float4 o0, o1;
  o0.x = fmaxf(0.f, f[0] * sa.x + ha.x);
  o0.y = fmaxf(0.f, f[1] * sa.y + ha.y);
  o0.z = fmaxf(0.f, f[2] * sa.z + ha.z);
  o0.w = fmaxf(0.f, f[3] * sa.w + ha.w);
  o1.x = fmaxf(0.f, f[4] * sb.x + hb.x);
  o1.y = fmaxf(0.f, f[5] * sb.y + hb.y);
  o1.z = fmaxf(0.f, f[6] * sb.z + hb.z);
  o1.w = fmaxf(0.f, f[7] * sb.w + hb.w);
  *(float4*)(out + idx) = o0;
  *(float4*)(out + idx + 4) = o1;
}

// ---------------- launch ---------------------------------------------------
extern "C" void kernel_launch(void* const* d_in, const int* in_sizes, int n_in,
                              void* d_out, int out_size, void* d_ws, size_t ws_size,
                              hipStream_t stream)
{
  (void)in_sizes; (void)n_in; (void)out_size; (void)ws_size;
  const float* Fj  = (const float*)d_in[0];
  const float* Fs  = (const float*)d_in[1];
  const float* Fe  = (const float*)d_in[2];
  const float* Wq  = (const float*)d_in[3];
  const float* bq  = (const float*)d_in[4];
  const float* Wsk = (const float*)d_in[5];
  const float* bsk = (const float*)d_in[6];
  const float* Wsv = (const float*)d_in[7];
  const float* bsv = (const float*)d_in[8];
  const float* Wek = (const float*)d_in[9];
  const float* bek = (const float*)d_in[10];
  const float* Wev = (const float*)d_in[11];
  const float* bev = (const float*)d_in[12];
  const float* lng = (const float*)d_in[13];
  const float* lnb = (const float*)d_in[14];
  const float* Wf  = (const float*)d_in[15];
  const float* bfp = (const float*)d_in[16];
  const float* bng = (const float*)d_in[17];
  const float* bnb = (const float*)d_in[18];

  char* ws = (char*)d_ws;
  // region map (bytes); peak ~276 MiB (< 288 MiB known-safe)
  bf16* FjB = (bf16*)(ws);                    // 64 MiB: Fj_bf -> T2
  bf16* T2  = FjB;
  bf16* Qb  = (bf16*)(ws + 67108864L);        // 64 MiB: Q -> Y
  bf16* Yb  = Qb;
  bf16* FT  = (bf16*)(ws + 134217728L);       // 32 MiB: FsT -> FeT
  bf16* Sq  = (bf16*)(ws + 167772160L);       // 32 MiB: S quarter (8 batches)
  bf16* Kb  = (bf16*)(ws + 201326592L);       // 8 MiB: K quarter
  bf16* Vt  = (bf16*)(ws + 209715200L);       // 8 MiB: Vt quarter
  bf16* T1  = (bf16*)(ws + 218103808L);       // 64 MiB
  bf16* Wt5 = (bf16*)(ws + 285212672L);       // 5 x 512KiB transposed weights
  bf16* WfB = (bf16*)(ws + 287834112L);       // 1 MiB
  float* stats = (float*)(ws + 288882688L);
  float* ssbuf = (float*)(ws + 288886784L);
  float* outp = (float*)d_out;

  const long PB_Q  = (long)LTOK * CDIM;      // 1048576  (per-batch Q/T/Fj elems)
  const long PB_KV = (long)HWTOK * CDIM;     // 524288
  const long PB_S  = (long)LTOK * HWTOK;     // 2097152

  dim3 blk(256);

  // --- conversions ---
  cvt_k<<<dim3(16384), blk, 0, stream>>>(Fj, FjB);                   // 32M elems
  cvt_k<<<dim3(256),   blk, 0, stream>>>(Wf, WfB);                   // 512K elems
  cvtT_k<<<dim3(8, 8, 1), blk, 0, stream>>>(Wq,  Wt5,            512, 512, 0);
  cvtT_k<<<dim3(8, 8, 1), blk, 0, stream>>>(Wsk, Wt5 + 262144,   512, 512, 0);
  cvtT_k<<<dim3(8, 8, 1), blk, 0, stream>>>(Wsv, Wt5 + 524288,   512, 512, 0);
  cvtT_k<<<dim3(8, 8, 1), blk, 0, stream>>>(Wek, Wt5 + 786432,   512, 512, 0);
  cvtT_k<<<dim3(8, 8, 1), blk, 0, stream>>>(Wev, Wt5 + 1048576,  512, 512, 0);

  // --- Q projection: [65536][512] = FjB @ WqT ---
  gemm_bt<1,false,false><<<dim3(4, 512, 1), blk, 0, stream>>>(
      FjB, nullptr, Wt5, bq, nullptr, Qb, 512, 512, 0, 0, 0);

  for (int attn = 0; attn < 2; attn++) {
    const float* Fsrc = attn ? Fe : Fs;
    const bf16* WkT = Wt5 + (attn ? 786432 : 262144);
    const bf16* WvT = Wt5 + (attn ? 1048576 : 524288);
    const float* bk = attn ? bek : bsk;
    const float* bv = attn ? bev : bsv;
    bf16* Tout = attn ? T2 : T1;

    // FT[b][m][c] = transpose of Fsrc view [b][c][m]
    cvtT_k<<<dim3(16, 8, 32), blk, 0, stream>>>(Fsrc, FT, 512, 1024, PB_KV);

    for (int q = 0; q < 4; q++) {
      const bf16* FTq = FT + (long)q * 8 * PB_KV;
      // K quarter: [1024][512] per batch
      gemm_bt<1,false,false><<<dim3(4, 8, 8), blk, 0, stream>>>(
          FTq, nullptr, WkT, bk, nullptr, Kb, 512, 512, PB_KV, 0, PB_KV);
      // Vt quarter: [512 d][1024 m] per batch  (A = WvT, B = FTq, row bias)
      gemm_bt<2,false,false><<<dim3(8, 4, 8), blk, 0, stream>>>(
          WvT, nullptr, FTq, bv, nullptr, Vt, 1024, 512, 0, PB_KV, PB_KV);
      // S quarter: [2048][1024] per batch
      gemm_bt<0,false,false><<<dim3(8, 16, 8), blk, 0, stream>>>(
          Qb + (long)q * 8 * PB_Q, nullptr, Kb, nullptr, nullptr, Sq,
          1024, 512, PB_Q, PB_KV, PB_S);
      // softmax in place (16384 rows)
      softmax_k<<<dim3(4096), blk, 0, stream>>>(Sq);
      // PV quarter + residual F_j (f32) -> Tout
      gemm_bt<0,false,true><<<dim3(4, 16, 8), blk, 0, stream>>>(
          Sq, nullptr, Vt, nullptr, Fj + (long)q * 8 * PB_Q,
          Tout + (long)q * 8 * PB_Q, 512, 1024, PB_S, PB_KV, PB_Q);
    }
    // LayerNorm in place over all 65536 rows
    ln_k<<<dim3(16384), blk, 0, stream>>>(Tout, lng, lnb);
  }

  // --- fusion conv1d: Y = [T1|T2] @ Wf^T + bf ---
  gemm_bt<1,true,false><<<dim3(4, 512, 1), blk, 0, stream>>>(
      T1, T2, WfB, bfp, nullptr, Yb, 512, 1024, 0, 0, 0);

  // --- BatchNorm (train stats) + ReLU -> f32 out ---
  (void)hipMemsetAsync(stats, 0, 4096, stream);
  bn_stats_k<<<dim3(2048), blk, 0, stream>>>(Yb, stats);
  bn_finalize_k<<<dim3(1), dim3(512), 0, stream>>>(stats, bng, bnb, ssbuf);
  bn_apply_k<<<dim3(16384), blk, 0, stream>>>(Yb, ssbuf, outp);
}